// Round 7
// baseline (90.233 us; speedup 1.0000x reference)
//
#include <hip/hip_runtime.h>
#include <math.h>

// Problem constants (fixed by setup_inputs)
constexpr int B_ = 8;
constexpr int N_ = 16384;
constexpr int M_ = 1024;
constexpr int C_ = 256;
constexpr int NCHUNK = 8;
constexpr int CHUNK = M_ / NCHUNK;  // 128
constexpr int KEEP = 4;             // per-chunk survivors
constexpr int TOPK_BLOCK = 1024;    // 16 waves/block -> 2 blocks/CU -> 2 K$ streams

// native 4-float vector for __builtin_nontemporal_store (HIP's float4 is a
// class type the builtin rejects; ext_vector_type is accepted).
typedef float nfloat4 __attribute__((ext_vector_type(4)));

// 4-deep sorted-insert network on POSITIVE floats (P0<=P1<=P2<=P3 invariant).
// min + 3x v_med3_f32, all VOP3-legal, no SGPR operands.
#define INSERT4(P, u)                                              \
  {                                                                \
    const float o0 = P##0, o1 = P##1, o2 = P##2;                   \
    P##0 = fminf(o0, (u));                                         \
    P##1 = __builtin_amdgcn_fmed3f(o0, P##1, (u));                 \
    P##2 = __builtin_amdgcn_fmed3f(o1, P##2, (u));                 \
    P##3 = __builtin_amdgcn_fmed3f(o2, P##3, (u));                 \
  }

// ---------------------------------------------------------------------------
// Kernel 0 (fused prep): blocks [0,32) pack centroids; blocks [32, 32+2048)
// transpose centroid_f [B,C,M] -> fT [B,M,C] via 32x32 LDS tiles (+1 pad).
// ---------------------------------------------------------------------------
__global__ __launch_bounds__(256) void prep_kernel(
    const float* __restrict__ cxyz,  // [B, M, 3]
    const float* __restrict__ cf,    // [B, C, M]
    float* __restrict__ csoa,        // [B][NCHUNK][CHUNK/2][8]
    float4* __restrict__ cpack,      // [B*M]
    float* __restrict__ fT)          // [B, M, C]
{
  __shared__ float tile[32][33];
  const int tx = threadIdx.x;  // 0..31
  const int ty = threadIdx.y;  // 0..7
  if (blockIdx.x < 32) {
    // ---- pack role ----
    const int i = blockIdx.x * 256 + (ty * 32 + tx);  // global centroid id
    if (i < B_ * M_) {
      const int b = i >> 10;         // / M_
      const int m = i & (M_ - 1);
      const int chunk = m >> 7;      // / CHUNK
      const int mi = m & (CHUNK - 1);
      const int pair = mi >> 1;
      const int sub = mi & 1;
      const float x = cxyz[3 * i + 0];
      const float y = cxyz[3 * i + 1];
      const float z = cxyz[3 * i + 2];
      const float w = x * x + y * y + z * z;
      float* pb = csoa + ((((size_t)b * NCHUNK + chunk) * (CHUNK / 2)) + pair) * 8 + sub;
      pb[0] = x; pb[2] = y; pb[4] = z; pb[6] = w;
      cpack[i] = make_float4(x, y, z, w);
    }
  } else {
    // ---- transpose role ----
    const int bid = blockIdx.x - 32;       // 0..2047
    const int m0 = (bid & 31) * 32;        // M/32 = 32
    const int c0 = ((bid >> 5) & 7) * 32;  // C/32 = 8
    const int b = bid >> 8;
    const float* fb = cf + (size_t)b * C_ * M_;
    float* ftb = fT + (size_t)b * M_ * C_;
#pragma unroll
    for (int j = 0; j < 32; j += 8)
      tile[ty + j][tx] = fb[(size_t)(c0 + ty + j) * M_ + (m0 + tx)];
    __syncthreads();
#pragma unroll
    for (int j = 0; j < 32; j += 8)
      ftb[(size_t)(m0 + ty + j) * C_ + (c0 + tx)] = tile[tx][ty + j];
  }
}

// ---------------------------------------------------------------------------
// Kernel 1: chunked top-4 -- VERBATIM best-measured R5 structure (86.4us),
// with ONE change: cand is now CHUNK-MAJOR [B][NCHUNK][N], so each wave's
// 64x4B writes are 256B contiguous (old point-major layout scattered them
// at stride 32B across 2KB).
// DO NOT fuse other roles into this kernel (R1/R2 lesson: union-kernel
// regalloc broke its 64-VGPR/8-wave-per-SIMD contract, 167-183us).
// ---------------------------------------------------------------------------
__global__ __launch_bounds__(TOPK_BLOCK) void topk_chunk_kernel(
    const float* __restrict__ xyz,   // [B, N, 3]
    const float* __restrict__ csoa,  // [B][NCHUNK][CHUNK/2][8]
    unsigned* __restrict__ cand)     // [B][NCHUNK][N]: 4 packed 8-bit indices
{
  const int b = blockIdx.z;
  const int chunk = blockIdx.y;
  const int n = blockIdx.x * TOPK_BLOCK + threadIdx.x;
  const size_t p = (size_t)b * N_ + n;

  const float* __restrict__ cb =
      csoa + (((size_t)b * NCHUNK + chunk) * (CHUNK / 2)) * 8;

  const float* xp = xyz + p * 3;
  const float x0 = xp[0], x1 = xp[1], x2 = xp[2];
  const float nx0 = -2.f * x0, nx1 = -2.f * x1, nx2 = -2.f * x2;
  const float x2p1 = fmaf(x0, x0, fmaf(x1, x1, fmaf(x2, x2, 1.0f)));

  float A0 = INFINITY, A1 = INFINITY, A2 = INFINITY, A3 = INFINITY;
  float B0 = INFINITY, B1 = INFINITY, B2 = INFINITY, B3 = INFINITY;

#pragma unroll 8
  for (int i = 0; i < CHUNK / 2; ++i) {
    const float* pb = cb + i * 8;
    float tx = fmaf(nx0, pb[0], x2p1), ty = fmaf(nx0, pb[1], x2p1);
    tx = fmaf(nx1, pb[2], tx); ty = fmaf(nx1, pb[3], ty);
    tx = fmaf(nx2, pb[4], tx); ty = fmaf(nx2, pb[5], ty);
    tx += pb[6]; ty += pb[7];  // key = d^2 + 1 > 0
    // pack 7-bit local index into low mantissa bits
    const float kx = __uint_as_float((__float_as_uint(tx) & 0xFFFFFF80u) | (unsigned)(2 * i));
    const float ky = __uint_as_float((__float_as_uint(ty) & 0xFFFFFF80u) | (unsigned)(2 * i + 1));
    INSERT4(A, kx);
    INSERT4(B, ky);
  }
  // fold chain B into chain A (exact running-inserts)
  INSERT4(A, B0);
  INSERT4(A, B1);
  INSERT4(A, B2);
  INSERT4(A, B3);

  const unsigned i0 = __float_as_uint(A0) & 127u;
  const unsigned i1 = __float_as_uint(A1) & 127u;
  const unsigned i2 = __float_as_uint(A2) & 127u;
  const unsigned i3 = __float_as_uint(A3) & 127u;
  // chunk-major: consecutive n -> consecutive words -> coalesced wave write
  cand[((size_t)(b * NCHUNK + chunk) << 14) + n] =
      i0 | (i1 << 8) | (i2 << 16) | (i3 << 24);
}

// ---------------------------------------------------------------------------
// Kernel 2 (fused merge+gather, grid-preserving -- fixes the R4 mistake):
// 16384 blocks x 256 threads, 8 points per block.
//   Phase A (lane-parallel merge): tid = pt*32 + j; lane j computes the f64
//     key kd for candidate j (ch=j>>2, slot=j&3) of point pt -- arithmetic
//     copied verbatim from the proven merge kernel. Top-3 via width-32
//     shuffle butterfly minimizing lexicographic (kd, j): identical
//     selection to the old strict-< scan, whose scan order ch-then-slot IS
//     j-ascending. Weights computed with the exact same float expressions.
//   Phase B (gather): proven R5 pattern -- wave-per-point rows (2 points
//     per wave), fT rows 1KB coalesced, nt stores for the 134MB output.
// Batch<->XCD swizzle (R5, -8us) kept: batch == blockIdx & 7.
// Saves: merge launch + gap, 6MB idx/w round-trip. Gather MLP preserved
// (65536 waves >> 8192 wave slots).
// ---------------------------------------------------------------------------
__global__ __launch_bounds__(256) void mg_kernel(
    const float* __restrict__ xyz,     // [B, N, 3]
    const float4* __restrict__ cpack,  // [B*M]
    const unsigned* __restrict__ cand, // [B][NCHUNK][N]
    const float* __restrict__ fT,      // [B, M, C]
    float* __restrict__ out)           // [B, N, C]
{
  __shared__ int   sI[8 * 3];
  __shared__ float sW[8 * 3];
  const int tid = threadIdx.x;
  // batch<->XCD swizzle: 16384 blocks, 2048 per batch, 8 points per block.
  const int g = (blockIdx.x & 7) * 2048 + (blockIdx.x >> 3);
  const size_t pbase = (size_t)g * 8;
  const int b = (int)(pbase >> 14);  // == blockIdx.x & 7

  {  // ---- Phase A: lane-parallel merge ----
    const int pt = tid >> 5;        // 0..7 point within block
    const unsigned j = tid & 31;    // candidate slot: ch=j>>2, sl=j&3
    const size_t p = pbase + pt;
    const int n = (int)(p - (size_t)b * N_);

    const float* xp = xyz + p * 3;
    const double x0d = (double)xp[0], x1d = (double)xp[1], x2d = (double)xp[2];

    const int ch = (int)(j >> 2), sl = (int)(j & 3);
    const unsigned word = cand[((size_t)(b * NCHUNK + ch) << 14) + n];
    const int m = ch * CHUNK + (int)((word >> (8 * sl)) & 255u);
    const float4 c = cpack[(size_t)b * M_ + m];
    const double cx = (double)c.x, cy = (double)c.y, cz = (double)c.z;
    const double dot = x0d * cx + x1d * cy + x2d * cz;
    const double c2d = cx * cx + cy * cy + cz * cz;
    double cur = c2d - 2.0 * dot;   // kd, verbatim expression

    double D0 = 0, D1 = 0, D2 = 0;
    int I0 = 0, I1 = 0, I2 = 0;
#pragma unroll
    for (int r = 0; r < 3; ++r) {
      double bk = cur;
      unsigned bj = j;
#pragma unroll
      for (int off = 16; off; off >>= 1) {
        const double ok = __shfl_xor(bk, off, 32);
        const unsigned oj = __shfl_xor(bj, off, 32);
        const bool take = (ok < bk) || (ok == bk && oj < bj);
        bk = take ? ok : bk;
        bj = take ? oj : bj;
      }
      // (bk, bj) uniform within the 32-lane group
      const int mw = __shfl(m, (int)bj, 32);
      if (r == 0)      { D0 = bk; I0 = mw; }
      else if (r == 1) { D1 = bk; I1 = mw; }
      else             { D2 = bk; I2 = mw; }
      if (j == bj) cur = 1e300;  // retire winner
    }

    // weights: exact float expressions from the proven merge kernel
    const double xx = x0d * x0d + x1d * x1d + x2d * x2d;
    const float d0 = sqrtf(fmaxf((float)(xx + D0), 0.0f));
    const float d1 = sqrtf(fmaxf((float)(xx + D1), 0.0f));
    const float d2 = sqrtf(fmaxf((float)(xx + D2), 0.0f));
    float w0 = 1.0f / fmaxf(d0, 1e-8f);
    float w1 = 1.0f / fmaxf(d1, 1e-8f);
    float w2 = 1.0f / fmaxf(d2, 1e-8f);
    const float wsum = w0 + w1 + w2;
    w0 /= wsum; w1 /= wsum; w2 /= wsum;

    if (j == 0) {
      sI[pt * 3 + 0] = I0; sI[pt * 3 + 1] = I1; sI[pt * 3 + 2] = I2;
      sW[pt * 3 + 0] = w0; sW[pt * 3 + 1] = w1; sW[pt * 3 + 2] = w2;
    }
  }
  __syncthreads();

  // ---- Phase B: gather (proven pattern; 2 points per wave; nt store) ----
  const int wid = tid >> 6;
  const int lane = tid & 63;
  const float4* __restrict__ f4 = (const float4*)(fT + (size_t)b * M_ * C_);
#pragma unroll
  for (int k = 0; k < 2; ++k) {
    const int li = wid * 2 + k;
    const size_t p = pbase + li;
    const int i0 = sI[li * 3 + 0], i1 = sI[li * 3 + 1], i2 = sI[li * 3 + 2];
    const float w0 = sW[li * 3 + 0], w1 = sW[li * 3 + 1], w2 = sW[li * 3 + 2];

    float4 a  = f4[(size_t)i0 * (C_ / 4) + lane];
    float4 bb = f4[(size_t)i1 * (C_ / 4) + lane];
    float4 c  = f4[(size_t)i2 * (C_ / 4) + lane];

    nfloat4 r;
    r.x = w0 * a.x + w1 * bb.x + w2 * c.x;
    r.y = w0 * a.y + w1 * bb.y + w2 * c.y;
    r.z = w0 * a.z + w1 * bb.z + w2 * c.z;
    r.w = w0 * a.w + w1 * bb.w + w2 * c.w;

    __builtin_nontemporal_store(r, &((nfloat4*)out)[p * (C_ / 4) + lane]);
  }
}

extern "C" void kernel_launch(void* const* d_in, const int* in_sizes, int n_in,
                              void* d_out, int out_size, void* d_ws, size_t ws_size,
                              hipStream_t stream) {
  const float* xyz  = (const float*)d_in[0];  // [B, N, 3]
  const float* cxyz = (const float*)d_in[1];  // [B, M, 3]
  const float* cf   = (const float*)d_in[2];  // [B, C, M]
  float* out = (float*)d_out;                 // [B, N, C]

  char* ws = (char*)d_ws;
  const size_t npts = (size_t)B_ * N_;

  float4* cpack = (float4*)ws;                          // B*M float4 (128 KB)
  size_t off = (size_t)B_ * M_ * sizeof(float4);
  float* csoa = (float*)(ws + off);                     // B*M*4 floats (128 KB)
  off += (size_t)B_ * M_ * 4 * sizeof(float);
  off = (off + 255) & ~(size_t)255;
  unsigned* cand = (unsigned*)(ws + off);               // B*8*N*4B = 4.2 MB
  off += ((size_t)B_ * NCHUNK * N_ * 4 + 255) & ~(size_t)255;
  float* fT = (float*)(ws + off);                       // B*M*C floats = 8 MB

  prep_kernel<<<dim3(32 + 2048), dim3(32, 8), 0, stream>>>(
      cxyz, cf, csoa, cpack, fT);
  topk_chunk_kernel<<<dim3(N_ / TOPK_BLOCK, NCHUNK, B_), TOPK_BLOCK, 0, stream>>>(
      xyz, csoa, cand);
  mg_kernel<<<(unsigned)(npts / 8), 256, 0, stream>>>(
      xyz, cpack, cand, fT, out);
}

// Round 8
// 87.195 us; speedup vs baseline: 1.0348x; 1.0348x over previous
//
#include <hip/hip_runtime.h>
#include <math.h>

// Problem constants (fixed by setup_inputs)
constexpr int B_ = 8;
constexpr int N_ = 16384;
constexpr int M_ = 1024;
constexpr int C_ = 256;
constexpr int NCHUNK = 8;
constexpr int CHUNK = M_ / NCHUNK;  // 128
constexpr int KEEP = 4;             // per-chunk survivors
constexpr int TOPK_BLOCK = 1024;    // 16 waves/block -> 2 blocks/CU -> 2 K$ streams

// DIAGNOSTIC ROUND (R8): topk's chunk-scan runs TOPK_REPS times with a
// memory clobber between reps (forces re-load + re-compute; stores are
// idempotent so output is byte-identical). dur_us = base + (REPS-1)*T
// pins topk's true duration T, and at 5T > 80us the topk dispatch
// surfaces above the harness poison-fills in the rocprof top-5,
// exposing its VALUBusy/Occupancy for the first time.
constexpr int TOPK_REPS = 5;

// native 4-float vector for __builtin_nontemporal_store (HIP's float4 is a
// class type the builtin rejects; ext_vector_type is accepted).
typedef float nfloat4 __attribute__((ext_vector_type(4)));

// 4-deep sorted-insert network on POSITIVE floats (P0<=P1<=P2<=P3 invariant).
// min + 3x v_med3_f32, all VOP3-legal, no SGPR operands.
#define INSERT4(P, u)                                              \
  {                                                                \
    const float o0 = P##0, o1 = P##1, o2 = P##2;                   \
    P##0 = fminf(o0, (u));                                         \
    P##1 = __builtin_amdgcn_fmed3f(o0, P##1, (u));                 \
    P##2 = __builtin_amdgcn_fmed3f(o1, P##2, (u));                 \
    P##3 = __builtin_amdgcn_fmed3f(o2, P##3, (u));                 \
  }

// ---------------------------------------------------------------------------
// Kernel 0 (fused prep): blocks [0,32) pack centroids; blocks [32, 32+2048)
// transpose centroid_f [B,C,M] -> fT [B,M,C] via 32x32 LDS tiles (+1 pad).
// ---------------------------------------------------------------------------
__global__ __launch_bounds__(256) void prep_kernel(
    const float* __restrict__ cxyz,  // [B, M, 3]
    const float* __restrict__ cf,    // [B, C, M]
    float* __restrict__ csoa,        // [B][NCHUNK][CHUNK/2][8]
    float4* __restrict__ cpack,      // [B*M]
    float* __restrict__ fT)          // [B, M, C]
{
  __shared__ float tile[32][33];
  const int tx = threadIdx.x;  // 0..31
  const int ty = threadIdx.y;  // 0..7
  if (blockIdx.x < 32) {
    // ---- pack role ----
    const int i = blockIdx.x * 256 + (ty * 32 + tx);  // global centroid id
    if (i < B_ * M_) {
      const int b = i >> 10;         // / M_
      const int m = i & (M_ - 1);
      const int chunk = m >> 7;      // / CHUNK
      const int mi = m & (CHUNK - 1);
      const int pair = mi >> 1;
      const int sub = mi & 1;
      const float x = cxyz[3 * i + 0];
      const float y = cxyz[3 * i + 1];
      const float z = cxyz[3 * i + 2];
      const float w = x * x + y * y + z * z;
      float* pb = csoa + ((((size_t)b * NCHUNK + chunk) * (CHUNK / 2)) + pair) * 8 + sub;
      pb[0] = x; pb[2] = y; pb[4] = z; pb[6] = w;
      cpack[i] = make_float4(x, y, z, w);
    }
  } else {
    // ---- transpose role ----
    const int bid = blockIdx.x - 32;       // 0..2047
    const int m0 = (bid & 31) * 32;        // M/32 = 32
    const int c0 = ((bid >> 5) & 7) * 32;  // C/32 = 8
    const int b = bid >> 8;
    const float* fb = cf + (size_t)b * C_ * M_;
    float* ftb = fT + (size_t)b * M_ * C_;
#pragma unroll
    for (int j = 0; j < 32; j += 8)
      tile[ty + j][tx] = fb[(size_t)(c0 + ty + j) * M_ + (m0 + tx)];
    __syncthreads();
#pragma unroll
    for (int j = 0; j < 32; j += 8)
      ftb[(size_t)(m0 + ty + j) * C_ + (c0 + tx)] = tile[tx][ty + j];
  }
}

// ---------------------------------------------------------------------------
// Kernel 1: chunked top-4 -- R5 structure, AMPLIFIED x5 for measurement.
// Each rep recomputes the full scan (memory clobber forces re-load) and
// rewrites the same cand word (idempotent). T_topk = (dur-base)/4.
// ---------------------------------------------------------------------------
__global__ __launch_bounds__(TOPK_BLOCK) void topk_chunk_kernel(
    const float* __restrict__ xyz,   // [B, N, 3]
    const float* __restrict__ csoa,  // [B][NCHUNK][CHUNK/2][8]
    unsigned* __restrict__ cand)     // [B*N][NCHUNK]: 4 packed 8-bit indices
{
  const int b = blockIdx.z;
  const int chunk = blockIdx.y;
  const int n = blockIdx.x * TOPK_BLOCK + threadIdx.x;
  const size_t p = (size_t)b * N_ + n;

  const float* __restrict__ cb =
      csoa + (((size_t)b * NCHUNK + chunk) * (CHUNK / 2)) * 8;

  const float* xp = xyz + p * 3;
  const float x0 = xp[0], x1 = xp[1], x2 = xp[2];
  const float nx0 = -2.f * x0, nx1 = -2.f * x1, nx2 = -2.f * x2;
  const float x2p1 = fmaf(x0, x0, fmaf(x1, x1, fmaf(x2, x2, 1.0f)));

  for (int rep = 0; rep < TOPK_REPS; ++rep) {
    float A0 = INFINITY, A1 = INFINITY, A2 = INFINITY, A3 = INFINITY;
    float B0 = INFINITY, B1 = INFINITY, B2 = INFINITY, B3 = INFINITY;

#pragma unroll 8
    for (int i = 0; i < CHUNK / 2; ++i) {
      const float* pb = cb + i * 8;
      float tx = fmaf(nx0, pb[0], x2p1), ty = fmaf(nx0, pb[1], x2p1);
      tx = fmaf(nx1, pb[2], tx); ty = fmaf(nx1, pb[3], ty);
      tx = fmaf(nx2, pb[4], tx); ty = fmaf(nx2, pb[5], ty);
      tx += pb[6]; ty += pb[7];  // key = d^2 + 1 > 0
      // pack 7-bit local index into low mantissa bits
      const float kx = __uint_as_float((__float_as_uint(tx) & 0xFFFFFF80u) | (unsigned)(2 * i));
      const float ky = __uint_as_float((__float_as_uint(ty) & 0xFFFFFF80u) | (unsigned)(2 * i + 1));
      INSERT4(A, kx);
      INSERT4(B, ky);
    }
    // fold chain B into chain A (exact running-inserts)
    INSERT4(A, B0);
    INSERT4(A, B1);
    INSERT4(A, B2);
    INSERT4(A, B3);

    const unsigned i0 = __float_as_uint(A0) & 127u;
    const unsigned i1 = __float_as_uint(A1) & 127u;
    const unsigned i2 = __float_as_uint(A2) & 127u;
    const unsigned i3 = __float_as_uint(A3) & 127u;
    cand[p * NCHUNK + chunk] = i0 | (i1 << 8) | (i2 << 16) | (i3 << 24);
    // force re-load + re-compute next rep (prevents CSE across reps);
    // register-held point data (x2p1 etc.) legitimately persists.
    asm volatile("" ::: "memory");
  }
}

// ---------------------------------------------------------------------------
// Kernel 2: merge 8x4 candidates -> exact global top-3 + weights. VERBATIM
// proven structure (f64 re-rank, stable strict-< insertion).
// ---------------------------------------------------------------------------
__global__ __launch_bounds__(256) void merge_kernel(
    const float* __restrict__ xyz,     // [B, N, 3]
    const float4* __restrict__ cpack,  // [B*M]
    const unsigned* __restrict__ cand, // [B*N][NCHUNK]
    int*   __restrict__ out_idx,       // [B*N, 3]
    float* __restrict__ out_w)         // [B*N, 3]
{
  const size_t p = (size_t)blockIdx.x * 256 + threadIdx.x;
  const int b = (int)(p >> 14);  // p / N_

  const float* xp = xyz + p * 3;
  const double x0d = (double)xp[0], x1d = (double)xp[1], x2d = (double)xp[2];
  const float4* __restrict__ cb = cpack + (size_t)b * M_;

  const uint4* cw4 = (const uint4*)(cand + p * NCHUNK);
  const uint4 ca = cw4[0], cb2 = cw4[1];
  unsigned words[NCHUNK] = {ca.x, ca.y, ca.z, ca.w, cb2.x, cb2.y, cb2.z, cb2.w};

  double D0 = 1e300, D1 = 1e300, D2 = 1e300;
  int I0 = 0, I1 = 0, I2 = 0;
#pragma unroll
  for (int ch = 0; ch < NCHUNK; ++ch) {
    const unsigned w = words[ch];
#pragma unroll
    for (int j = 0; j < KEEP; ++j) {
      const int m = ch * CHUNK + (int)((w >> (8 * j)) & 255u);
      const float4 c = cb[m];
      const double cx = (double)c.x, cy = (double)c.y, cz = (double)c.z;
      const double dot = x0d * cx + x1d * cy + x2d * cz;
      const double c2d = cx * cx + cy * cy + cz * cz;
      const double kd = c2d - 2.0 * dot;
      if (kd < D2) {
        if (kd < D1) {
          D2 = D1; I2 = I1;
          if (kd < D0) { D1 = D0; I1 = I0; D0 = kd; I0 = m; }
          else         { D1 = kd; I1 = m; }
        } else {
          D2 = kd; I2 = m;
        }
      }
    }
  }

  const double xx = x0d * x0d + x1d * x1d + x2d * x2d;
  const float d0 = sqrtf(fmaxf((float)(xx + D0), 0.0f));
  const float d1 = sqrtf(fmaxf((float)(xx + D1), 0.0f));
  const float d2 = sqrtf(fmaxf((float)(xx + D2), 0.0f));
  float w0 = 1.0f / fmaxf(d0, 1e-8f);
  float w1 = 1.0f / fmaxf(d1, 1e-8f);
  float w2 = 1.0f / fmaxf(d2, 1e-8f);
  const float wsum = w0 + w1 + w2;
  w0 /= wsum; w1 /= wsum; w2 /= wsum;

  const size_t o = p * 3;
  out_idx[o + 0] = I0; out_idx[o + 1] = I1; out_idx[o + 2] = I2;
  out_w[o + 0] = w0;   out_w[o + 1] = w1;   out_w[o + 2] = w2;
}

// ---------------------------------------------------------------------------
// Kernel 3: weighted feature gather -- VERBATIM R5 (batch<->XCD swizzle +
// non-temporal output stores; 8us win over baseline).
// ---------------------------------------------------------------------------
__global__ __launch_bounds__(256) void gather_kernel(
    const float* __restrict__ fT,   // [B, M, C]
    const int*   __restrict__ idx,  // [B*N, 3]
    const float* __restrict__ w,    // [B*N, 3]
    float* __restrict__ out)        // [B, N, C]
{
  const int wid  = threadIdx.x >> 6;
  const int lane = threadIdx.x & 63;
  // batch<->XCD swizzle: 32768 groups of 4 points; 4096 groups per batch.
  const int g = (blockIdx.x & 7) * 4096 + (blockIdx.x >> 3);
  const size_t p = (size_t)g * 4 + wid;  // global point id
  const int b = (int)(p >> 14);          // p / N_  (== blockIdx.x & 7)

  const size_t o = p * 3;
  const int i0 = idx[o + 0], i1 = idx[o + 1], i2 = idx[o + 2];
  const float w0 = w[o + 0], w1 = w[o + 1], w2 = w[o + 2];

  const float4* f4 = (const float4*)(fT + (size_t)b * M_ * C_);
  float4 a = f4[(size_t)i0 * (C_ / 4) + lane];
  float4 bb = f4[(size_t)i1 * (C_ / 4) + lane];
  float4 c = f4[(size_t)i2 * (C_ / 4) + lane];

  nfloat4 r;
  r.x = w0 * a.x + w1 * bb.x + w2 * c.x;
  r.y = w0 * a.y + w1 * bb.y + w2 * c.y;
  r.z = w0 * a.z + w1 * bb.z + w2 * c.z;
  r.w = w0 * a.w + w1 * bb.w + w2 * c.w;

  __builtin_nontemporal_store(r, &((nfloat4*)out)[p * (C_ / 4) + lane]);
}

extern "C" void kernel_launch(void* const* d_in, const int* in_sizes, int n_in,
                              void* d_out, int out_size, void* d_ws, size_t ws_size,
                              hipStream_t stream) {
  const float* xyz  = (const float*)d_in[0];  // [B, N, 3]
  const float* cxyz = (const float*)d_in[1];  // [B, M, 3]
  const float* cf   = (const float*)d_in[2];  // [B, C, M]
  float* out = (float*)d_out;                 // [B, N, C]

  char* ws = (char*)d_ws;
  const size_t npts = (size_t)B_ * N_;

  int*    idxbuf = (int*)ws;                              // npts*3 ints
  float*  wbuf   = (float*)(ws + npts * 3 * sizeof(int)); // npts*3 floats
  size_t  off    = npts * 3 * 8;
  float4* cpack  = (float4*)(ws + off);                   // B*M float4 (128 KB)
  off += (size_t)B_ * M_ * sizeof(float4);
  float*  csoa   = (float*)(ws + off);                    // B*M*4 floats (128 KB)
  off += (size_t)B_ * M_ * 4 * sizeof(float);
  off = (off + 15) & ~(size_t)15;
  char*   region = ws + off;
  unsigned* cand = (unsigned*)region;  // npts*NCHUNK*4B = 4.2 MB
  size_t cand_bytes = (npts * (size_t)NCHUNK * 4 + 255) & ~(size_t)255;
  float* fT = (float*)(region + cand_bytes);  // B*M*C floats = 8 MB

  prep_kernel<<<dim3(32 + 2048), dim3(32, 8), 0, stream>>>(
      cxyz, cf, csoa, cpack, fT);
  topk_chunk_kernel<<<dim3(N_ / TOPK_BLOCK, NCHUNK, B_), TOPK_BLOCK, 0, stream>>>(
      xyz, csoa, cand);
  merge_kernel<<<(unsigned)(npts / 256), 256, 0, stream>>>(
      xyz, cpack, cand, idxbuf, wbuf);
  gather_kernel<<<(unsigned)(npts / 4), 256, 0, stream>>>(fT, idxbuf, wbuf, out);
}

// Round 10
// 87.030 us; speedup vs baseline: 1.0368x; 1.0019x over previous
//
#include <hip/hip_runtime.h>
#include <math.h>

// Problem constants (fixed by setup_inputs)
constexpr int B_ = 8;
constexpr int N_ = 16384;
constexpr int M_ = 1024;
constexpr int C_ = 256;
constexpr int NCHUNK = 8;
constexpr int CHUNK = M_ / NCHUNK;  // 128
constexpr int KEEP = 4;             // per-chunk survivors
constexpr int TOPK_BLOCK = 1024;    // 16 waves/block -> 2 blocks/CU -> 2 K$ streams

// DIAGNOSTIC ROUND (R9b): amplification with laundered base offsets.
// R8's version was defeated by const+restrict (loads hoisted); R9 fixed
// that but put the gather offset in divergent data -> illegal VGPR->SGPR
// copy. Here gather's batch comes straight from blockIdx (b = blockIdx&7,
// scalar by construction) so "+s" laundering is legal. Stores idempotent
// -> output byte-identical. topk x5, gather x3:
//   dur = base + 4*T_topk + 2*T_gather; both amplified dispatches
//   (expected ~90us each) surface in the rocprof top-5 with counters.
constexpr int TOPK_REPS = 5;
constexpr int GATHER_REPS = 3;

// native 4-float vector for __builtin_nontemporal_store (HIP's float4 is a
// class type the builtin rejects; ext_vector_type is accepted).
typedef float nfloat4 __attribute__((ext_vector_type(4)));

// 4-deep sorted-insert network on POSITIVE floats (P0<=P1<=P2<=P3 invariant).
#define INSERT4(P, u)                                              \
  {                                                                \
    const float o0 = P##0, o1 = P##1, o2 = P##2;                   \
    P##0 = fminf(o0, (u));                                         \
    P##1 = __builtin_amdgcn_fmed3f(o0, P##1, (u));                 \
    P##2 = __builtin_amdgcn_fmed3f(o1, P##2, (u));                 \
    P##3 = __builtin_amdgcn_fmed3f(o2, P##3, (u));                 \
  }

// ---------------------------------------------------------------------------
// Kernel 0 (fused prep): blocks [0,32) pack centroids; blocks [32, 32+2048)
// transpose centroid_f [B,C,M] -> fT [B,M,C] via 32x32 LDS tiles (+1 pad).
// ---------------------------------------------------------------------------
__global__ __launch_bounds__(256) void prep_kernel(
    const float* __restrict__ cxyz,  // [B, M, 3]
    const float* __restrict__ cf,    // [B, C, M]
    float* __restrict__ csoa,        // [B][NCHUNK][CHUNK/2][8]
    float4* __restrict__ cpack,      // [B*M]
    float* __restrict__ fT)          // [B, M, C]
{
  __shared__ float tile[32][33];
  const int tx = threadIdx.x;  // 0..31
  const int ty = threadIdx.y;  // 0..7
  if (blockIdx.x < 32) {
    // ---- pack role ----
    const int i = blockIdx.x * 256 + (ty * 32 + tx);  // global centroid id
    if (i < B_ * M_) {
      const int b = i >> 10;         // / M_
      const int m = i & (M_ - 1);
      const int chunk = m >> 7;      // / CHUNK
      const int mi = m & (CHUNK - 1);
      const int pair = mi >> 1;
      const int sub = mi & 1;
      const float x = cxyz[3 * i + 0];
      const float y = cxyz[3 * i + 1];
      const float z = cxyz[3 * i + 2];
      const float w = x * x + y * y + z * z;
      float* pb = csoa + ((((size_t)b * NCHUNK + chunk) * (CHUNK / 2)) + pair) * 8 + sub;
      pb[0] = x; pb[2] = y; pb[4] = z; pb[6] = w;
      cpack[i] = make_float4(x, y, z, w);
    }
  } else {
    // ---- transpose role ----
    const int bid = blockIdx.x - 32;       // 0..2047
    const int m0 = (bid & 31) * 32;        // M/32 = 32
    const int c0 = ((bid >> 5) & 7) * 32;  // C/32 = 8
    const int b = bid >> 8;
    const float* fb = cf + (size_t)b * C_ * M_;
    float* ftb = fT + (size_t)b * M_ * C_;
#pragma unroll
    for (int j = 0; j < 32; j += 8)
      tile[ty + j][tx] = fb[(size_t)(c0 + ty + j) * M_ + (m0 + tx)];
    __syncthreads();
#pragma unroll
    for (int j = 0; j < 32; j += 8)
      ftb[(size_t)(m0 + ty + j) * C_ + (c0 + tx)] = tile[tx][ty + j];
  }
}

// ---------------------------------------------------------------------------
// Kernel 1: chunked top-4 -- R5 structure, AMPLIFIED x5 with laundered
// base offset (true recompute; scalar-load codegen preserved via "+s";
// cbo is blockIdx-only -> SGPR-legal).
// T_topk = this dispatch's rocprof dur / 5.
// ---------------------------------------------------------------------------
__global__ __launch_bounds__(TOPK_BLOCK) void topk_chunk_kernel(
    const float* __restrict__ xyz,   // [B, N, 3]
    const float* __restrict__ csoa,  // [B][NCHUNK][CHUNK/2][8]
    unsigned* __restrict__ cand)     // [B*N][NCHUNK]: 4 packed 8-bit indices
{
  const int b = blockIdx.z;
  const int chunk = blockIdx.y;
  const int n = blockIdx.x * TOPK_BLOCK + threadIdx.x;
  const size_t p = (size_t)b * N_ + n;

  unsigned long long cbo =
      (unsigned long long)((((size_t)b * NCHUNK + chunk) * (CHUNK / 2)) * 8);

  const float* xp = xyz + p * 3;
  const float x0 = xp[0], x1 = xp[1], x2 = xp[2];
  const float nx0 = -2.f * x0, nx1 = -2.f * x1, nx2 = -2.f * x2;
  const float x2p1 = fmaf(x0, x0, fmaf(x1, x1, fmaf(x2, x2, 1.0f)));

  for (int rep = 0; rep < TOPK_REPS; ++rep) {
    // launder the chunk base offset: opaque SGPR value -> loads below cannot
    // be CSE'd with a previous rep's loads, so the full scan + insert
    // network re-executes each rep.
    asm volatile("" : "+s"(cbo));
    const float* __restrict__ cb = csoa + cbo;

    float A0 = INFINITY, A1 = INFINITY, A2 = INFINITY, A3 = INFINITY;
    float B0 = INFINITY, B1 = INFINITY, B2 = INFINITY, B3 = INFINITY;

#pragma unroll 8
    for (int i = 0; i < CHUNK / 2; ++i) {
      const float* pb = cb + i * 8;
      float tx = fmaf(nx0, pb[0], x2p1), ty = fmaf(nx0, pb[1], x2p1);
      tx = fmaf(nx1, pb[2], tx); ty = fmaf(nx1, pb[3], ty);
      tx = fmaf(nx2, pb[4], tx); ty = fmaf(nx2, pb[5], ty);
      tx += pb[6]; ty += pb[7];  // key = d^2 + 1 > 0
      const float kx = __uint_as_float((__float_as_uint(tx) & 0xFFFFFF80u) | (unsigned)(2 * i));
      const float ky = __uint_as_float((__float_as_uint(ty) & 0xFFFFFF80u) | (unsigned)(2 * i + 1));
      INSERT4(A, kx);
      INSERT4(B, ky);
    }
    INSERT4(A, B0);
    INSERT4(A, B1);
    INSERT4(A, B2);
    INSERT4(A, B3);

    const unsigned i0 = __float_as_uint(A0) & 127u;
    const unsigned i1 = __float_as_uint(A1) & 127u;
    const unsigned i2 = __float_as_uint(A2) & 127u;
    const unsigned i3 = __float_as_uint(A3) & 127u;
    cand[p * NCHUNK + chunk] = i0 | (i1 << 8) | (i2 << 16) | (i3 << 24);
  }
}

// ---------------------------------------------------------------------------
// Kernel 2: merge 8x4 candidates -> exact global top-3 + weights. VERBATIM
// proven structure (f64 re-rank, stable strict-< insertion). 1x.
// ---------------------------------------------------------------------------
__global__ __launch_bounds__(256) void merge_kernel(
    const float* __restrict__ xyz,     // [B, N, 3]
    const float4* __restrict__ cpack,  // [B*M]
    const unsigned* __restrict__ cand, // [B*N][NCHUNK]
    int*   __restrict__ out_idx,       // [B*N, 3]
    float* __restrict__ out_w)         // [B*N, 3]
{
  const size_t p = (size_t)blockIdx.x * 256 + threadIdx.x;
  const int b = (int)(p >> 14);  // p / N_

  const float* xp = xyz + p * 3;
  const double x0d = (double)xp[0], x1d = (double)xp[1], x2d = (double)xp[2];
  const float4* __restrict__ cb = cpack + (size_t)b * M_;

  const uint4* cw4 = (const uint4*)(cand + p * NCHUNK);
  const uint4 ca = cw4[0], cb2 = cw4[1];
  unsigned words[NCHUNK] = {ca.x, ca.y, ca.z, ca.w, cb2.x, cb2.y, cb2.z, cb2.w};

  double D0 = 1e300, D1 = 1e300, D2 = 1e300;
  int I0 = 0, I1 = 0, I2 = 0;
#pragma unroll
  for (int ch = 0; ch < NCHUNK; ++ch) {
    const unsigned w = words[ch];
#pragma unroll
    for (int j = 0; j < KEEP; ++j) {
      const int m = ch * CHUNK + (int)((w >> (8 * j)) & 255u);
      const float4 c = cb[m];
      const double cx = (double)c.x, cy = (double)c.y, cz = (double)c.z;
      const double dot = x0d * cx + x1d * cy + x2d * cz;
      const double c2d = cx * cx + cy * cy + cz * cz;
      const double kd = c2d - 2.0 * dot;
      if (kd < D2) {
        if (kd < D1) {
          D2 = D1; I2 = I1;
          if (kd < D0) { D1 = D0; I1 = I0; D0 = kd; I0 = m; }
          else         { D1 = kd; I1 = m; }
        } else {
          D2 = kd; I2 = m;
        }
      }
    }
  }

  const double xx = x0d * x0d + x1d * x1d + x2d * x2d;
  const float d0 = sqrtf(fmaxf((float)(xx + D0), 0.0f));
  const float d1 = sqrtf(fmaxf((float)(xx + D1), 0.0f));
  const float d2 = sqrtf(fmaxf((float)(xx + D2), 0.0f));
  float w0 = 1.0f / fmaxf(d0, 1e-8f);
  float w1 = 1.0f / fmaxf(d1, 1e-8f);
  float w2 = 1.0f / fmaxf(d2, 1e-8f);
  const float wsum = w0 + w1 + w2;
  w0 /= wsum; w1 /= wsum; w2 /= wsum;

  const size_t o = p * 3;
  out_idx[o + 0] = I0; out_idx[o + 1] = I1; out_idx[o + 2] = I2;
  out_w[o + 0] = w0;   out_w[o + 1] = w1;   out_w[o + 2] = w2;
}

// ---------------------------------------------------------------------------
// Kernel 3: weighted feature gather -- R5 structure (batch<->XCD swizzle +
// nt stores), AMPLIFIED x3 with laundered fT offset. b and fo come ONLY
// from blockIdx (scalar) -> "+s" is legal (R9 crash fix).
// T_gather = this dispatch's rocprof dur / 3; its FETCH_SIZE tells whether
// fT reads are L2-resident (small) or HBM (large).
// ---------------------------------------------------------------------------
__global__ __launch_bounds__(256) void gather_kernel(
    const float* __restrict__ fT,   // [B, M, C]
    const int*   __restrict__ idx,  // [B*N, 3]
    const float* __restrict__ w,    // [B*N, 3]
    float* __restrict__ out)        // [B, N, C]
{
  const int wid  = threadIdx.x >> 6;
  const int lane = threadIdx.x & 63;
  // batch<->XCD swizzle: 32768 groups of 4 points; 4096 groups per batch.
  const int b = (int)(blockIdx.x & 7);            // scalar by construction
  const int g = b * 4096 + (int)(blockIdx.x >> 3);
  const size_t p = (size_t)g * 4 + wid;           // global point id

  const size_t o = p * 3;
  const int i0 = idx[o + 0], i1 = idx[o + 1], i2 = idx[o + 2];
  const float w0 = w[o + 0], w1 = w[o + 1], w2 = w[o + 2];

  unsigned long long fo = (unsigned long long)b * (M_ * (C_ / 4));

  for (int rep = 0; rep < GATHER_REPS; ++rep) {
    asm volatile("" : "+s"(fo));  // opaque scalar base -> loads re-execute
    const float4* f4 = (const float4*)fT + fo;
    float4 a = f4[(size_t)i0 * (C_ / 4) + lane];
    float4 bb = f4[(size_t)i1 * (C_ / 4) + lane];
    float4 c = f4[(size_t)i2 * (C_ / 4) + lane];

    nfloat4 r;
    r.x = w0 * a.x + w1 * bb.x + w2 * c.x;
    r.y = w0 * a.y + w1 * bb.y + w2 * c.y;
    r.z = w0 * a.z + w1 * bb.z + w2 * c.z;
    r.w = w0 * a.w + w1 * bb.w + w2 * c.w;

    __builtin_nontemporal_store(r, &((nfloat4*)out)[p * (C_ / 4) + lane]);
  }
}

extern "C" void kernel_launch(void* const* d_in, const int* in_sizes, int n_in,
                              void* d_out, int out_size, void* d_ws, size_t ws_size,
                              hipStream_t stream) {
  const float* xyz  = (const float*)d_in[0];  // [B, N, 3]
  const float* cxyz = (const float*)d_in[1];  // [B, M, 3]
  const float* cf   = (const float*)d_in[2];  // [B, C, M]
  float* out = (float*)d_out;                 // [B, N, C]

  char* ws = (char*)d_ws;
  const size_t npts = (size_t)B_ * N_;

  int*    idxbuf = (int*)ws;                              // npts*3 ints
  float*  wbuf   = (float*)(ws + npts * 3 * sizeof(int)); // npts*3 floats
  size_t  off    = npts * 3 * 8;
  float4* cpack  = (float4*)(ws + off);                   // B*M float4 (128 KB)
  off += (size_t)B_ * M_ * sizeof(float4);
  float*  csoa   = (float*)(ws + off);                    // B*M*4 floats (128 KB)
  off += (size_t)B_ * M_ * 4 * sizeof(float);
  off = (off + 15) & ~(size_t)15;
  char*   region = ws + off;
  unsigned* cand = (unsigned*)region;  // npts*NCHUNK*4B = 4.2 MB
  size_t cand_bytes = (npts * (size_t)NCHUNK * 4 + 255) & ~(size_t)255;
  float* fT = (float*)(region + cand_bytes);  // B*M*C floats = 8 MB

  prep_kernel<<<dim3(32 + 2048), dim3(32, 8), 0, stream>>>(
      cxyz, cf, csoa, cpack, fT);
  topk_chunk_kernel<<<dim3(N_ / TOPK_BLOCK, NCHUNK, B_), TOPK_BLOCK, 0, stream>>>(
      xyz, csoa, cand);
  merge_kernel<<<(unsigned)(npts / 256), 256, 0, stream>>>(
      xyz, cpack, cand, idxbuf, wbuf);
  gather_kernel<<<(unsigned)(npts / 4), 256, 0, stream>>>(fT, idxbuf, wbuf, out);
}